// Round 5
// baseline (275.190 us; speedup 1.0000x reference)
//
#include <hip/hip_runtime.h>
#include <hip/hip_bf16.h>

typedef __bf16 bf16_t;
typedef __bf16 bf16x4_t __attribute__((ext_vector_type(4)));
typedef __bf16 bf16x8  __attribute__((ext_vector_type(8)));
typedef float  f32x4   __attribute__((ext_vector_type(4)));

#define T_LEN 200
#define D_DIM 256

__device__ __forceinline__ float fast_tanh(float x) {
    float e = __expf(2.0f * x);
    return 1.0f - 2.0f / (e + 1.0f);
}

// ---------------------------------------------------------------------------
// Kernel 1a: qpart[b][d] = sum_k Q[b][k] * W1[d][k]  (f32) -> d_out (scratch)
// ---------------------------------------------------------------------------
__global__ __launch_bounds__(256) void qpart_kernel(
    const float* __restrict__ Q, const float* __restrict__ W1,
    float* __restrict__ Out)
{
    __shared__ float qs[8][256];
    const int tid = threadIdx.x;
    const int b0  = blockIdx.x * 8;
    for (int idx = tid; idx < 8 * 256; idx += 256)
        qs[idx >> 8][idx & 255] = Q[(size_t)(b0 + (idx >> 8)) * 256 + (idx & 255)];
    __syncthreads();
    float acc[8];
    #pragma unroll
    for (int i = 0; i < 8; ++i) acc[i] = 0.f;
    const f32x4* Wv = (const f32x4*)(W1 + (size_t)tid * 512);
    #pragma unroll 4
    for (int k4 = 0; k4 < 64; ++k4) {
        f32x4 w = Wv[k4];
        #pragma unroll
        for (int bb = 0; bb < 8; ++bb) {
            f32x4 qv = *(const f32x4*)&qs[bb][k4 * 4];
            acc[bb] += qv[0]*w[0] + qv[1]*w[1] + qv[2]*w[2] + qv[3]*w[3];
        }
    }
    #pragma unroll
    for (int bb = 0; bb < 8; ++bb)
        Out[(size_t)(b0 + bb) * 256 + tid] = acc[bb];
}

// ---------------------------------------------------------------------------
// Kernel 1b: W1b (= W1[:,256:512]) -> bf16, row-major [256][256] in ws.
// ---------------------------------------------------------------------------
__global__ __launch_bounds__(256) void convw_kernel(
    const float* __restrict__ W1, bf16_t* __restrict__ bfW)
{
    const int d = blockIdx.x;
    const int k = threadIdx.x;
    bfW[(size_t)d * 256 + k] = (bf16_t)W1[(size_t)d * 512 + 256 + k];
}

// ---------------------------------------------------------------------------
// Kernel 2 (v5): one (batch, quarter) per block; SWAPPED MFMA operands.
//   A = W1b (register-held, rows = d), B = ub^T from LDS (cols = t)
//   => C[row=d][col=t]: the W2-dot over d is IN-LANE (8 fma) + 2 shfl + 1
//      atomic per t-tile (was 16 shfl + 4 atomics). Tail latency ~4x less.
//   MFMA batched 2 t-tiles per cluster: 32 back-to-back MFMAs, 4 acc chains.
//   Quarters: rows {56,56,56,32} staged as {64,64,64,32} (zero-pad; pad t's
//   get p=0 in the exp phase). No-max softmax (|s| <= ||W2||_1 ~ 13).
//   Partial numerator/denominator -> ws; combine kernel divides.
// ---------------------------------------------------------------------------
template<bool SPLIT>
__global__ __launch_bounds__(512, 4) void attn_v5_kernel(
    const float* __restrict__ U,      // [B,200,256]
    const int*   __restrict__ Mask,   // [B,200]
    const float* __restrict__ W1,     // [256,512] (fallback frag source)
    const float* __restrict__ W2,     // [256]
    const bf16_t* __restrict__ bfW,   // [256][256] bf16 W1b (SPLIT only)
    float* Out,                       // qpart on entry; !SPLIT: final out
    float* __restrict__ WsNum,        // [grid][256] (SPLIT)
    float* __restrict__ WsL)          // [grid]      (SPLIT)
{
    constexpr int MAXROW = SPLIT ? 64 : 224;
    __shared__ bf16_t tiles[MAXROW * 256];   // 32 KB / 112 KB, XOR-swizzled
    __shared__ float score_lds[MAXROW];
    __shared__ float p_lds[MAXROW];
    __shared__ float out_lds[4][256];
    __shared__ float l_red;

    const int tid  = threadIdx.x;
    const int lane = tid & 63;
    const int wv   = tid >> 6;   // wave 0..7 -> d block [wv*32, wv*32+32)
    const int lr   = lane & 15;
    const int lg   = lane >> 4;

    int b, t0, nrow, nreal;
    if (SPLIT) {
        b = blockIdx.x >> 2;
        const int h = blockIdx.x & 3;
        t0    = h * 56;
        nreal = (h == 3) ? 32 : 56;
        nrow  = (h == 3) ? 32 : 64;
    } else {
        b = blockIdx.x; t0 = 0; nreal = 200; nrow = 224;
    }
    char* const tbase = (char*)tiles;

    if (tid < nrow) score_lds[tid] = 0.f;
    if (tid == 0)   l_red = 0.f;

    // ---- A-fragments: W1b rows d = wv*32 + sub*16 + lr (64 VGPR) ----
    bf16x8 aw[2][8];
    #pragma unroll
    for (int sub = 0; sub < 2; ++sub) {
        const int d = wv * 32 + sub * 16 + lr;
        if (SPLIT) {
            #pragma unroll
            for (int kk = 0; kk < 8; ++kk)
                aw[sub][kk] = *(const bf16x8*)(bfW + (size_t)d * 256 + kk * 32 + lg * 8);
        } else {
            const float* wrow = W1 + (size_t)d * 512 + 256;
            #pragma unroll
            for (int kk = 0; kk < 8; ++kk) {
                const float* s = wrow + kk * 32 + lg * 8;
                f32x4 lo = *(const f32x4*)s;
                f32x4 hi = *(const f32x4*)(s + 4);
                bf16x8 v;
                v[0]=(bf16_t)lo[0]; v[1]=(bf16_t)lo[1]; v[2]=(bf16_t)lo[2]; v[3]=(bf16_t)lo[3];
                v[4]=(bf16_t)hi[0]; v[5]=(bf16_t)hi[1]; v[6]=(bf16_t)hi[2]; v[7]=(bf16_t)hi[3];
                aw[sub][kk] = v;
            }
        }
    }
    // per-lane d for C rows: d = wv*32 + sub*16 + lg*4 + r
    float w2v[2][4], qpv[2][4];
    #pragma unroll
    for (int sub = 0; sub < 2; ++sub)
        #pragma unroll
        for (int r = 0; r < 4; ++r) {
            const int d = wv * 32 + sub * 16 + lg * 4 + r;
            w2v[sub][r] = W2[d];
            qpv[sub][r] = Out[(size_t)b * 256 + d];
        }

    // ---- stage rows (wave-owned, branchless except pad rows) ----
    {
        const float* Ub = U + (size_t)b * (T_LEN * D_DIM);
        const int ni = nrow >> 3;
        for (int i = 0; i < ni; ++i) {
            const int r = wv + i * 8;
            bf16x4_t v;
            v[0]=(bf16_t)0.f; v[1]=(bf16_t)0.f; v[2]=(bf16_t)0.f; v[3]=(bf16_t)0.f;
            if (r < nreal) {
                f32x4 g = *(const f32x4*)(Ub + (size_t)(t0 + r) * 256 + lane * 4);
                v[0]=(bf16_t)g[0]; v[1]=(bf16_t)g[1]; v[2]=(bf16_t)g[2]; v[3]=(bf16_t)g[3];
            }
            *(bf16x4_t*)(tbase + r * 512 + ((lane * 8) ^ ((r & 7) << 4))) = v;
        }
    }
    __syncthreads();

    // ---- compute: 2 t-tiles per MFMA cluster ----
    const int npair = nrow >> 5;
    for (int pp = 0; pp < npair; ++pp) {
        f32x4 a00 = {0,0,0,0}, a01 = {0,0,0,0};   // tile g=0: sub 0,1
        f32x4 a10 = {0,0,0,0}, a11 = {0,0,0,0};   // tile g=1: sub 0,1
        const int r0 = pp * 32 + lr;
        const int r1 = r0 + 16;
        __builtin_amdgcn_s_setprio(1);
        #pragma unroll
        for (int kk = 0; kk < 8; ++kk) {
            const unsigned kb = (unsigned)(kk * 64 + lg * 16);
            bf16x8 u0 = *(const bf16x8*)(tbase + r0 * 512 + (kb ^ (((unsigned)r0 & 7) << 4)));
            bf16x8 u1 = *(const bf16x8*)(tbase + r1 * 512 + (kb ^ (((unsigned)r1 & 7) << 4)));
            a00 = __builtin_amdgcn_mfma_f32_16x16x32_bf16(aw[0][kk], u0, a00, 0, 0, 0);
            a01 = __builtin_amdgcn_mfma_f32_16x16x32_bf16(aw[1][kk], u0, a01, 0, 0, 0);
            a10 = __builtin_amdgcn_mfma_f32_16x16x32_bf16(aw[0][kk], u1, a10, 0, 0, 0);
            a11 = __builtin_amdgcn_mfma_f32_16x16x32_bf16(aw[1][kk], u1, a11, 0, 0, 0);
        }
        __builtin_amdgcn_s_setprio(0);

        // tails: in-lane weighted tanh sum over 8 d's, 2 shfl, 1 atomic
        float s0 = 0.f, s1 = 0.f;
        #pragma unroll
        for (int r = 0; r < 4; ++r) {
            s0 += w2v[0][r] * fast_tanh(a00[r] + qpv[0][r]);
            s0 += w2v[1][r] * fast_tanh(a01[r] + qpv[1][r]);
            s1 += w2v[0][r] * fast_tanh(a10[r] + qpv[0][r]);
            s1 += w2v[1][r] * fast_tanh(a11[r] + qpv[1][r]);
        }
        s0 += __shfl_xor(s0, 16); s0 += __shfl_xor(s0, 32);
        s1 += __shfl_xor(s1, 16); s1 += __shfl_xor(s1, 32);
        if (lg == 0) {
            atomicAdd(&score_lds[pp * 32 + lr], s0);
            atomicAdd(&score_lds[pp * 32 + 16 + lr], s1);
        }
    }
    __syncthreads();   // scores complete

    // ---- p = exp(masked s) (no-max), denominator ----
    {
        float p = 0.f;
        if (tid < nreal)
            p = Mask[(size_t)b * T_LEN + t0 + tid] ? 1.0f : __expf(score_lds[tid]);
        if (tid < nrow) p_lds[tid] = p;   // pad rows stay 0
        float ps = p;
        ps += __shfl_xor(ps, 1);
        ps += __shfl_xor(ps, 2);
        ps += __shfl_xor(ps, 4);
        ps += __shfl_xor(ps, 8);
        ps += __shfl_xor(ps, 16);
        ps += __shfl_xor(ps, 32);
        if (lane == 0 && ps != 0.f) atomicAdd(&l_red, ps);
    }
    __syncthreads();   // p, l ready

    // ---- PV from LDS bf16 ----
    {
        const int dp = tid & 127;   // bf16 pair {2dp, 2dp+1}
        const int jg = tid >> 7;
        const int qr = nrow >> 2;
        float o0 = 0.f, o1 = 0.f;
        for (int i = 0; i < qr; ++i) {
            const int j = jg * qr + i;
            const float p = p_lds[j];
            const unsigned w = *(const unsigned*)(tbase + j * 512
                             + (((unsigned)(dp * 4)) ^ (((unsigned)j & 7) << 4)));
            o0 += p * __builtin_bit_cast(float, w << 16);
            o1 += p * __builtin_bit_cast(float, w & 0xffff0000u);
        }
        *(float2*)&out_lds[jg][dp * 2] = make_float2(o0, o1);
    }
    __syncthreads();

    if (tid < 256) {
        const float num = out_lds[0][tid] + out_lds[1][tid]
                        + out_lds[2][tid] + out_lds[3][tid];
        if (SPLIT) WsNum[(size_t)blockIdx.x * 256 + tid] = num;
        else       Out[(size_t)b * 256 + tid] = num / l_red;
    }
    if (SPLIT && tid == 0) WsL[blockIdx.x] = l_red;
}

// ---------------------------------------------------------------------------
// Kernel 3: out[b][d] = sum_h num[h] / sum_h l[h]   (4 quarters)
// ---------------------------------------------------------------------------
__global__ __launch_bounds__(256) void combine_kernel(
    const float* __restrict__ WsNum, const float* __restrict__ WsL,
    float* __restrict__ Out)
{
    const int b = blockIdx.x, tid = threadIdx.x;
    float n = 0.f;
    #pragma unroll
    for (int h = 0; h < 4; ++h)
        n += WsNum[(size_t)(4 * b + h) * 256 + tid];
    const float l = WsL[4*b] + WsL[4*b+1] + WsL[4*b+2] + WsL[4*b+3];
    Out[(size_t)b * 256 + tid] = n / l;
}

extern "C" void kernel_launch(void* const* d_in, const int* in_sizes, int n_in,
                              void* d_out, int out_size, void* d_ws, size_t ws_size,
                              hipStream_t stream)
{
    const float* Q  = (const float*)d_in[0];
    const float* U  = (const float*)d_in[1];
    const int*   Mk = (const int*)d_in[2];
    const float* W1 = (const float*)d_in[3];
    const float* W2 = (const float*)d_in[4];
    float* Out = (float*)d_out;
    const int B = in_sizes[0] / D_DIM;   // 2048

    qpart_kernel<<<dim3(B / 8), dim3(256), 0, stream>>>(Q, W1, Out);

    const size_t nblk = (size_t)B * 4;
    const size_t need = nblk * 256 * 4 + nblk * 4 + 256 * 256 * 2;
    if (ws_size >= need) {
        float*  wsn = (float*)d_ws;
        float*  wsl = wsn + nblk * 256;
        bf16_t* bfw = (bf16_t*)(wsl + nblk);
        convw_kernel<<<dim3(256), dim3(256), 0, stream>>>(W1, bfw);
        attn_v5_kernel<true><<<dim3((unsigned)nblk), dim3(512), 0, stream>>>(
            U, Mk, W1, W2, bfw, Out, wsn, wsl);
        combine_kernel<<<dim3(B), dim3(256), 0, stream>>>(wsn, wsl, Out);
    } else {
        attn_v5_kernel<false><<<dim3(B), dim3(512), 0, stream>>>(
            U, Mk, W1, W2, nullptr, Out, nullptr, nullptr);
    }
}

// Round 6
// 275.187 us; speedup vs baseline: 1.0000x; 1.0000x over previous
//
#include <hip/hip_runtime.h>
#include <hip/hip_bf16.h>

typedef __bf16 bf16_t;
typedef __bf16 bf16x4_t __attribute__((ext_vector_type(4)));
typedef __bf16 bf16x8  __attribute__((ext_vector_type(8)));
typedef float  f32x4   __attribute__((ext_vector_type(4)));

#define T_LEN 200
#define D_DIM 256

__device__ __forceinline__ float fast_tanh(float x) {
    float e = __expf(2.0f * x);
    return 1.0f - 2.0f / (e + 1.0f);
}

// ---------------------------------------------------------------------------
// Kernel 1a: qpart[b][d] = sum_k Q[b][k] * W1[d][k]  (f32) -> d_out (scratch)
// ---------------------------------------------------------------------------
__global__ __launch_bounds__(256) void qpart_kernel(
    const float* __restrict__ Q, const float* __restrict__ W1,
    float* __restrict__ Out)
{
    __shared__ float qs[8][256];
    const int tid = threadIdx.x;
    const int b0  = blockIdx.x * 8;
    for (int idx = tid; idx < 8 * 256; idx += 256)
        qs[idx >> 8][idx & 255] = Q[(size_t)(b0 + (idx >> 8)) * 256 + (idx & 255)];
    __syncthreads();
    float acc[8];
    #pragma unroll
    for (int i = 0; i < 8; ++i) acc[i] = 0.f;
    const f32x4* Wv = (const f32x4*)(W1 + (size_t)tid * 512);
    #pragma unroll 4
    for (int k4 = 0; k4 < 64; ++k4) {
        f32x4 w = Wv[k4];
        #pragma unroll
        for (int bb = 0; bb < 8; ++bb) {
            f32x4 qv = *(const f32x4*)&qs[bb][k4 * 4];
            acc[bb] += qv[0]*w[0] + qv[1]*w[1] + qv[2]*w[2] + qv[3]*w[3];
        }
    }
    #pragma unroll
    for (int bb = 0; bb < 8; ++bb)
        Out[(size_t)(b0 + bb) * 256 + tid] = acc[bb];
}

// ---------------------------------------------------------------------------
// Kernel 1b: W1b (= W1[:,256:512]) -> bf16, row-major [256][256] in ws.
// ---------------------------------------------------------------------------
__global__ __launch_bounds__(256) void convw_kernel(
    const float* __restrict__ W1, bf16_t* __restrict__ bfW)
{
    const int d = blockIdx.x;
    const int k = threadIdx.x;
    bfW[(size_t)d * 256 + k] = (bf16_t)W1[(size_t)d * 512 + 256 + k];
}

// ---------------------------------------------------------------------------
// Kernel 2 (v5): one (batch, quarter) per block; SWAPPED MFMA operands.
//   A = W1b (register-held, rows = d), B = ub^T from LDS (cols = t)
//   => C[row=d][col=t]: the W2-dot over d is IN-LANE (8 fma) + 2 shfl + 1
//      atomic per t-tile (was 16 shfl + 4 atomics). Tail latency ~4x less.
//   MFMA batched 2 t-tiles per cluster: 32 back-to-back MFMAs, 4 acc chains.
//   Quarters: rows {56,56,56,32} staged as {64,64,64,32} (zero-pad; pad t's
//   get p=0 in the exp phase). No-max softmax (|s| <= ||W2||_1 ~ 13).
//   Partial numerator/denominator -> ws; combine kernel divides.
// ---------------------------------------------------------------------------
template<bool SPLIT>
__global__ __launch_bounds__(512, 4) void attn_v5_kernel(
    const float* __restrict__ U,      // [B,200,256]
    const int*   __restrict__ Mask,   // [B,200]
    const float* __restrict__ W1,     // [256,512] (fallback frag source)
    const float* __restrict__ W2,     // [256]
    const bf16_t* __restrict__ bfW,   // [256][256] bf16 W1b (SPLIT only)
    float* Out,                       // qpart on entry; !SPLIT: final out
    float* __restrict__ WsNum,        // [grid][256] (SPLIT)
    float* __restrict__ WsL)          // [grid]      (SPLIT)
{
    constexpr int MAXROW = SPLIT ? 64 : 224;
    __shared__ bf16_t tiles[MAXROW * 256];   // 32 KB / 112 KB, XOR-swizzled
    __shared__ float score_lds[MAXROW];
    __shared__ float p_lds[MAXROW];
    __shared__ float out_lds[4][256];
    __shared__ float l_red;

    const int tid  = threadIdx.x;
    const int lane = tid & 63;
    const int wv   = tid >> 6;   // wave 0..7 -> d block [wv*32, wv*32+32)
    const int lr   = lane & 15;
    const int lg   = lane >> 4;

    int b, t0, nrow, nreal;
    if (SPLIT) {
        b = blockIdx.x >> 2;
        const int h = blockIdx.x & 3;
        t0    = h * 56;
        nreal = (h == 3) ? 32 : 56;
        nrow  = (h == 3) ? 32 : 64;
    } else {
        b = blockIdx.x; t0 = 0; nreal = 200; nrow = 224;
    }
    char* const tbase = (char*)tiles;

    if (tid < nrow) score_lds[tid] = 0.f;
    if (tid == 0)   l_red = 0.f;

    // ---- A-fragments: W1b rows d = wv*32 + sub*16 + lr (64 VGPR) ----
    bf16x8 aw[2][8];
    #pragma unroll
    for (int sub = 0; sub < 2; ++sub) {
        const int d = wv * 32 + sub * 16 + lr;
        if (SPLIT) {
            #pragma unroll
            for (int kk = 0; kk < 8; ++kk)
                aw[sub][kk] = *(const bf16x8*)(bfW + (size_t)d * 256 + kk * 32 + lg * 8);
        } else {
            const float* wrow = W1 + (size_t)d * 512 + 256;
            #pragma unroll
            for (int kk = 0; kk < 8; ++kk) {
                const float* s = wrow + kk * 32 + lg * 8;
                f32x4 lo = *(const f32x4*)s;
                f32x4 hi = *(const f32x4*)(s + 4);
                bf16x8 v;
                v[0]=(bf16_t)lo[0]; v[1]=(bf16_t)lo[1]; v[2]=(bf16_t)lo[2]; v[3]=(bf16_t)lo[3];
                v[4]=(bf16_t)hi[0]; v[5]=(bf16_t)hi[1]; v[6]=(bf16_t)hi[2]; v[7]=(bf16_t)hi[3];
                aw[sub][kk] = v;
            }
        }
    }
    // per-lane d for C rows: d = wv*32 + sub*16 + lg*4 + r
    float w2v[2][4], qpv[2][4];
    #pragma unroll
    for (int sub = 0; sub < 2; ++sub)
        #pragma unroll
        for (int r = 0; r < 4; ++r) {
            const int d = wv * 32 + sub * 16 + lg * 4 + r;
            w2v[sub][r] = W2[d];
            qpv[sub][r] = Out[(size_t)b * 256 + d];
        }

    // ---- stage rows (wave-owned, branchless except pad rows) ----
    {
        const float* Ub = U + (size_t)b * (T_LEN * D_DIM);
        const int ni = nrow >> 3;
        for (int i = 0; i < ni; ++i) {
            const int r = wv + i * 8;
            bf16x4_t v;
            v[0]=(bf16_t)0.f; v[1]=(bf16_t)0.f; v[2]=(bf16_t)0.f; v[3]=(bf16_t)0.f;
            if (r < nreal) {
                f32x4 g = *(const f32x4*)(Ub + (size_t)(t0 + r) * 256 + lane * 4);
                v[0]=(bf16_t)g[0]; v[1]=(bf16_t)g[1]; v[2]=(bf16_t)g[2]; v[3]=(bf16_t)g[3];
            }
            *(bf16x4_t*)(tbase + r * 512 + ((lane * 8) ^ ((r & 7) << 4))) = v;
        }
    }
    __syncthreads();

    // ---- compute: 2 t-tiles per MFMA cluster ----
    const int npair = nrow >> 5;
    for (int pp = 0; pp < npair; ++pp) {
        f32x4 a00 = {0,0,0,0}, a01 = {0,0,0,0};   // tile g=0: sub 0,1
        f32x4 a10 = {0,0,0,0}, a11 = {0,0,0,0};   // tile g=1: sub 0,1
        const int r0 = pp * 32 + lr;
        const int r1 = r0 + 16;
        __builtin_amdgcn_s_setprio(1);
        #pragma unroll
        for (int kk = 0; kk < 8; ++kk) {
            const unsigned kb = (unsigned)(kk * 64 + lg * 16);
            bf16x8 u0 = *(const bf16x8*)(tbase + r0 * 512 + (kb ^ (((unsigned)r0 & 7) << 4)));
            bf16x8 u1 = *(const bf16x8*)(tbase + r1 * 512 + (kb ^ (((unsigned)r1 & 7) << 4)));
            a00 = __builtin_amdgcn_mfma_f32_16x16x32_bf16(aw[0][kk], u0, a00, 0, 0, 0);
            a01 = __builtin_amdgcn_mfma_f32_16x16x32_bf16(aw[1][kk], u0, a01, 0, 0, 0);
            a10 = __builtin_amdgcn_mfma_f32_16x16x32_bf16(aw[0][kk], u1, a10, 0, 0, 0);
            a11 = __builtin_amdgcn_mfma_f32_16x16x32_bf16(aw[1][kk], u1, a11, 0, 0, 0);
        }
        __builtin_amdgcn_s_setprio(0);

        // tails: in-lane weighted tanh sum over 8 d's, 2 shfl, 1 atomic
        float s0 = 0.f, s1 = 0.f;
        #pragma unroll
        for (int r = 0; r < 4; ++r) {
            s0 += w2v[0][r] * fast_tanh(a00[r] + qpv[0][r]);
            s0 += w2v[1][r] * fast_tanh(a01[r] + qpv[1][r]);
            s1 += w2v[0][r] * fast_tanh(a10[r] + qpv[0][r]);
            s1 += w2v[1][r] * fast_tanh(a11[r] + qpv[1][r]);
        }
        s0 += __shfl_xor(s0, 16); s0 += __shfl_xor(s0, 32);
        s1 += __shfl_xor(s1, 16); s1 += __shfl_xor(s1, 32);
        if (lg == 0) {
            atomicAdd(&score_lds[pp * 32 + lr], s0);
            atomicAdd(&score_lds[pp * 32 + 16 + lr], s1);
        }
    }
    __syncthreads();   // scores complete

    // ---- p = exp(masked s) (no-max), denominator ----
    {
        float p = 0.f;
        if (tid < nreal)
            p = Mask[(size_t)b * T_LEN + t0 + tid] ? 1.0f : __expf(score_lds[tid]);
        if (tid < nrow) p_lds[tid] = p;   // pad rows stay 0
        float ps = p;
        ps += __shfl_xor(ps, 1);
        ps += __shfl_xor(ps, 2);
        ps += __shfl_xor(ps, 4);
        ps += __shfl_xor(ps, 8);
        ps += __shfl_xor(ps, 16);
        ps += __shfl_xor(ps, 32);
        if (lane == 0 && ps != 0.f) atomicAdd(&l_red, ps);
    }
    __syncthreads();   // p, l ready

    // ---- PV from LDS bf16 ----
    {
        const int dp = tid & 127;   // bf16 pair {2dp, 2dp+1}
        const int jg = tid >> 7;
        const int qr = nrow >> 2;
        float o0 = 0.f, o1 = 0.f;
        for (int i = 0; i < qr; ++i) {
            const int j = jg * qr + i;
            const float p = p_lds[j];
            const unsigned w = *(const unsigned*)(tbase + j * 512
                             + (((unsigned)(dp * 4)) ^ (((unsigned)j & 7) << 4)));
            o0 += p * __builtin_bit_cast(float, w << 16);
            o1 += p * __builtin_bit_cast(float, w & 0xffff0000u);
        }
        *(float2*)&out_lds[jg][dp * 2] = make_float2(o0, o1);
    }
    __syncthreads();

    if (tid < 256) {
        const float num = out_lds[0][tid] + out_lds[1][tid]
                        + out_lds[2][tid] + out_lds[3][tid];
        if (SPLIT) WsNum[(size_t)blockIdx.x * 256 + tid] = num;
        else       Out[(size_t)b * 256 + tid] = num / l_red;
    }
    if (SPLIT && tid == 0) WsL[blockIdx.x] = l_red;
}

// ---------------------------------------------------------------------------
// Kernel 3: out[b][d] = sum_h num[h] / sum_h l[h]   (4 quarters)
// ---------------------------------------------------------------------------
__global__ __launch_bounds__(256) void combine_kernel(
    const float* __restrict__ WsNum, const float* __restrict__ WsL,
    float* __restrict__ Out)
{
    const int b = blockIdx.x, tid = threadIdx.x;
    float n = 0.f;
    #pragma unroll
    for (int h = 0; h < 4; ++h)
        n += WsNum[(size_t)(4 * b + h) * 256 + tid];
    const float l = WsL[4*b] + WsL[4*b+1] + WsL[4*b+2] + WsL[4*b+3];
    Out[(size_t)b * 256 + tid] = n / l;
}

extern "C" void kernel_launch(void* const* d_in, const int* in_sizes, int n_in,
                              void* d_out, int out_size, void* d_ws, size_t ws_size,
                              hipStream_t stream)
{
    const float* Q  = (const float*)d_in[0];
    const float* U  = (const float*)d_in[1];
    const int*   Mk = (const int*)d_in[2];
    const float* W1 = (const float*)d_in[3];
    const float* W2 = (const float*)d_in[4];
    float* Out = (float*)d_out;
    const int B = in_sizes[0] / D_DIM;   // 2048

    qpart_kernel<<<dim3(B / 8), dim3(256), 0, stream>>>(Q, W1, Out);

    const size_t nblk = (size_t)B * 4;
    const size_t need = nblk * 256 * 4 + nblk * 4 + 256 * 256 * 2;
    if (ws_size >= need) {
        float*  wsn = (float*)d_ws;
        float*  wsl = wsn + nblk * 256;
        bf16_t* bfw = (bf16_t*)(wsl + nblk);
        convw_kernel<<<dim3(256), dim3(256), 0, stream>>>(W1, bfw);
        attn_v5_kernel<true><<<dim3((unsigned)nblk), dim3(512), 0, stream>>>(
            U, Mk, W1, W2, bfw, Out, wsn, wsl);
        combine_kernel<<<dim3(B), dim3(256), 0, stream>>>(wsn, wsl, Out);
    } else {
        attn_v5_kernel<false><<<dim3(B), dim3(512), 0, stream>>>(
            U, Mk, W1, W2, nullptr, Out, nullptr, nullptr);
    }
}